// Round 3
// baseline (1707.373 us; speedup 1.0000x reference)
//
#include <hip/hip_runtime.h>

#define BB  1024
#define TT  1000
#define DD  6
#define HN  32
#define HHN 15

typedef float v2f __attribute__((ext_vector_type(2)));

__device__ __forceinline__ void pinv(v2f& v) {
    float x = v.x, y = v.y;
    asm volatile("" : "+v"(x), "+v"(y));
    v.x = x; v.y = y;
}
__device__ __forceinline__ void pinf(float& v) { asm volatile("" : "+v"(v)); }

// broadcast from uniform lane -> SGPR (VALU op, short latency; NOT a DS op)
__device__ __forceinline__ float bcastf(float v, int l) {
    return __uint_as_float(__builtin_amdgcn_readlane(__float_as_uint(v), l));
}
// add lane^1 partner via DPP quad_perm (fuses to v_add_f32_dpp)
__device__ __forceinline__ float qxadd1(float v) {
    int t = __builtin_amdgcn_update_dpp(0, __float_as_int(v), 0xB1, 0xF, 0xF, true);
    return v + __int_as_float(t);
}
// tanh(x) = 1 - 2/(exp2(2*log2e*x)+1); exact saturation, rel err ~1e-6
__device__ __forceinline__ float tanh_fast(float x) {
    float e = __builtin_amdgcn_exp2f(x * 2.885390081777927f);
    return fmaf(-2.0f, __builtin_amdgcn_rcpf(e + 1.0f), 1.0f);
}
__device__ __forceinline__ v2f vfma(v2f a, v2f b, v2f c) {
    return __builtin_elementwise_fma(a, b, c);
}

extern "C" __global__ void __launch_bounds__(64, 1)
cde_kernel(const float* __restrict__ coeffs,
           const float* __restrict__ W0, const float* __restrict__ b0,
           const float* __restrict__ W1, const float* __restrict__ b1,
           const float* __restrict__ W2, const float* __restrict__ b2,
           const float* __restrict__ W3, const float* __restrict__ b3,
           const float* __restrict__ W4, const float* __restrict__ b4,
           const float* __restrict__ Wf, const float* __restrict__ bf,
           float* __restrict__ out)
{
    const int b = blockIdx.x;
    const int L = threadIdx.x;               // one wave per block
    const float* cb = coeffs + (size_t)b * (TT * DD);

    // stage this block's coeffs in LDS (24 KB) — off the critical path
    __shared__ float xs[TT * DD];
    for (int idx = L; idx < TT * DD; idx += 64) xs[idx] = cb[idx];

    const int quad = L >> 2;                 // neuron owned for layers 1-3 (quads 0..14 valid)
    const int iq   = (quad < HHN) ? quad : (HHN - 1);
    const int par  = L & 1;                  // layer-4 d-slot parity

    // ---- persistent weights in VGPRs (pinned, packed) ----
    // layers 1-3: every lane of quad i holds the FULL column i (constant-indexed)
    v2f w1f[16];
    #pragma unroll
    for (int k2 = 0; k2 < 16; ++k2) {
        w1f[k2] = (v2f){ W1[(2 * k2) * HHN + iq], W1[(2 * k2 + 1) * HHN + iq] };
        pinv(w1f[k2]);
    }
    v2f w2f[8], w3f[8];
    #pragma unroll
    for (int k2 = 0; k2 < 8; ++k2) {
        float a2 = W2[(2 * k2) * HHN + iq];
        float c2 = (2 * k2 + 1 < HHN) ? W2[(2 * k2 + 1) * HHN + iq] : 0.f;
        w2f[k2] = (v2f){a2, c2}; pinv(w2f[k2]);
        float a3 = W3[(2 * k2) * HHN + iq];
        float c3 = (2 * k2 + 1 < HHN) ? W3[(2 * k2 + 1) * HHN + iq] : 0.f;
        w3f[k2] = (v2f){a3, c3}; pinv(w3f[k2]);
    }
    float bias1 = b1[iq]; pinf(bias1);
    float bias2 = b2[iq]; pinf(bias2);
    float bias3 = b3[iq]; pinf(bias3);

    // layer 4: lane owns cols c = 3L+q; pair (2j,2j+1) covers h-index j
    v2f w4f[3][8]; float bias4[3];
    #pragma unroll
    for (int q = 0; q < 3; ++q) {
        const int c = 3 * L + q;
        bias4[q] = b4[c]; pinf(bias4[q]);
        #pragma unroll
        for (int k2 = 0; k2 < 8; ++k2) {
            float a4 = W4[(2 * k2) * (HN * DD) + c];
            float c4 = (2 * k2 + 1 < HHN) ? W4[(2 * k2 + 1) * (HN * DD) + c] : 0.f;
            w4f[q][k2] = (v2f){a4, c4}; pinv(w4f[q][k2]);
        }
    }

    __syncthreads();

    // ---- h replicated in every lane: h2[j2] = {h[2j2], h[2j2+1]} ----
    v2f h2[16];
    #pragma unroll
    for (int j2 = 0; j2 < 16; ++j2) {
        v2f acc = (v2f){ b0[2 * j2], b0[2 * j2 + 1] };
        #pragma unroll
        for (int d = 0; d < DD; ++d) {
            v2f w = (v2f){ W0[d * HN + 2 * j2], W0[d * HN + 2 * j2 + 1] };
            acc = vfma((v2f){xs[d], xs[d]}, w, acc);
        }
        h2[j2] = acc;
    }

    const v2f* xsp = (const v2f*)xs;
    v2f xA[3], xB[3];
    #pragma unroll
    for (int e = 0; e < 3; ++e) { xA[e] = xsp[e]; xB[e] = xsp[3 + e]; }

    v2f g2[16];
    float dxl0, dxl1, dxl2;

    // one vector-field eval contracted with dx: y (replicated) -> g2 (replicated)
    auto evalg = [&](const v2f* y) {
        // layer 1: full 32-dot per lane for neuron iq
        v2f sa = (v2f){0.f, 0.f}, sb = (v2f){0.f, 0.f};
        #pragma unroll
        for (int k2 = 0; k2 < 16; k2 += 2) {
            sa = vfma(y[k2],     w1f[k2],     sa);
            sb = vfma(y[k2 + 1], w1f[k2 + 1], sb);
        }
        v2f s1 = sa + sb;
        const float z1 = fmaxf(s1.x + s1.y + bias1, 0.f);
        v2f z1p[8];
        #pragma unroll
        for (int i = 0; i < 7; ++i) z1p[i] = (v2f){ bcastf(z1, 8 * i), bcastf(z1, 8 * i + 4) };
        z1p[7] = (v2f){ bcastf(z1, 56), 0.f };

        // layer 2
        v2f s2a = (v2f){0.f, 0.f}, s2b = (v2f){0.f, 0.f};
        #pragma unroll
        for (int k2 = 0; k2 < 8; k2 += 2) {
            s2a = vfma(z1p[k2],     w2f[k2],     s2a);
            s2b = vfma(z1p[k2 + 1], w2f[k2 + 1], s2b);
        }
        v2f s2 = s2a + s2b;
        const float z2 = fmaxf(s2.x + s2.y + bias2, 0.f);
        v2f z2p[8];
        #pragma unroll
        for (int i = 0; i < 7; ++i) z2p[i] = (v2f){ bcastf(z2, 8 * i), bcastf(z2, 8 * i + 4) };
        z2p[7] = (v2f){ bcastf(z2, 56), 0.f };

        // layer 3
        v2f s3a = (v2f){0.f, 0.f}, s3b = (v2f){0.f, 0.f};
        #pragma unroll
        for (int k2 = 0; k2 < 8; k2 += 2) {
            s3a = vfma(z2p[k2],     w3f[k2],     s3a);
            s3b = vfma(z2p[k2 + 1], w3f[k2 + 1], s3b);
        }
        v2f s3 = s3a + s3b;
        const float z3 = fmaxf(s3.x + s3.y + bias3, 0.f);
        v2f z3p[8];
        #pragma unroll
        for (int i = 0; i < 7; ++i) z3p[i] = (v2f){ bcastf(z3, 8 * i), bcastf(z3, 8 * i + 4) };
        z3p[7] = (v2f){ bcastf(z3, 56), 0.f };

        // layer 4 + tanh + dot(dx): 3 cols per lane
        float partial = 0.f;
        #pragma unroll
        for (int q = 0; q < 3; ++q) {
            v2f s4a = (v2f){bias4[q], 0.f}, s4b = (v2f){0.f, 0.f};
            #pragma unroll
            for (int k2 = 0; k2 < 8; k2 += 2) {
                s4a = vfma(z3p[k2],     w4f[q][k2],     s4a);
                s4b = vfma(z3p[k2 + 1], w4f[q][k2 + 1], s4b);
            }
            v2f s4 = s4a + s4b;
            const float dq = (q == 0) ? dxl0 : ((q == 1) ? dxl1 : dxl2);
            partial = fmaf(tanh_fast(s4.x + s4.y), dq, partial);
        }
        // g[j] = partial(2j) + partial(2j+1): DPP xor-1 add (VALU, no LDS)
        partial = qxadd1(partial);
        // re-replicate g: g[j] lives on lane 2j
        #pragma unroll
        for (int j2 = 0; j2 < 16; ++j2)
            g2[j2] = (v2f){ bcastf(partial, 4 * j2), bcastf(partial, 4 * j2 + 2) };
    };

    const v2f C05 = (v2f){0.5f, 0.5f};
    const v2f C2  = (v2f){2.f, 2.f};
    const v2f C6  = (v2f){1.f / 6.f, 1.f / 6.f};

    #pragma unroll 1
    for (int t = 0; t < TT - 1; ++t) {
        v2f dxv[3];
        #pragma unroll
        for (int e = 0; e < 3; ++e) dxv[e] = xB[e] - xA[e];
        // even lane: d = {0,1,2}; odd lane: d = {3,4,5}
        dxl0 = par ? dxv[1].y : dxv[0].x;
        dxl1 = par ? dxv[2].x : dxv[0].y;
        dxl2 = par ? dxv[2].y : dxv[1].x;

        // prefetch x[t+2] (LDS latency hidden under ~1600 cy of compute)
        const int tn = (t + 2 < TT) ? (t + 2) : (TT - 1);
        v2f xN[3];
        #pragma unroll
        for (int e = 0; e < 3; ++e) xN[e] = xsp[tn * 3 + e];

        v2f y2[16], acc2[16];
        // k1
        evalg(h2);
        #pragma unroll
        for (int j2 = 0; j2 < 16; ++j2) { acc2[j2] = g2[j2]; y2[j2] = vfma(C05, g2[j2], h2[j2]); }
        // k2
        evalg(y2);
        #pragma unroll
        for (int j2 = 0; j2 < 16; ++j2) { acc2[j2] = vfma(C2, g2[j2], acc2[j2]); y2[j2] = vfma(C05, g2[j2], h2[j2]); }
        // k3
        evalg(y2);
        #pragma unroll
        for (int j2 = 0; j2 < 16; ++j2) { acc2[j2] = vfma(C2, g2[j2], acc2[j2]); y2[j2] = h2[j2] + g2[j2]; }
        // k4
        evalg(y2);
        #pragma unroll
        for (int j2 = 0; j2 < 16; ++j2) { h2[j2] = vfma(C6, acc2[j2] + g2[j2], h2[j2]); }

        #pragma unroll
        for (int e = 0; e < 3; ++e) { xA[e] = xB[e]; xB[e] = xN[e]; }
    }

    // ---- out[b] = h . Wf + bf (h replicated; compute everywhere, store lane 0) ----
    v2f accf = (v2f){0.f, 0.f};
    #pragma unroll
    for (int j2 = 0; j2 < 16; ++j2)
        accf = vfma(h2[j2], (v2f){ Wf[2 * j2], Wf[2 * j2 + 1] }, accf);
    if (L == 0) out[b] = accf.x + accf.y + bf[0];
}

extern "C" void kernel_launch(void* const* d_in, const int* in_sizes, int n_in,
                              void* d_out, int out_size, void* d_ws, size_t ws_size,
                              hipStream_t stream) {
    const float* coeffs = (const float*)d_in[0];
    const float* W0 = (const float*)d_in[1];
    const float* b0 = (const float*)d_in[2];
    const float* W1 = (const float*)d_in[3];
    const float* b1 = (const float*)d_in[4];
    const float* W2 = (const float*)d_in[5];
    const float* b2 = (const float*)d_in[6];
    const float* W3 = (const float*)d_in[7];
    const float* b3 = (const float*)d_in[8];
    const float* W4 = (const float*)d_in[9];
    const float* b4 = (const float*)d_in[10];
    const float* Wf = (const float*)d_in[11];
    const float* bf = (const float*)d_in[12];
    float* out = (float*)d_out;

    hipLaunchKernelGGL(cde_kernel, dim3(BB), dim3(64), 0, stream,
                       coeffs, W0, b0, W1, b1, W2, b2, W3, b3, W4, b4, Wf, bf, out);
}

// Round 4
// 1484.871 us; speedup vs baseline: 1.1498x; 1.1498x over previous
//
#include <hip/hip_runtime.h>

#define BB  1024
#define TT  1000
#define DD  6
#define HN  32
#define HHN 15

__device__ __forceinline__ void pinf(float& v) { asm volatile("" : "+v"(v)); }

// wave-uniform broadcast from lane l -> SGPR; used directly as the 1 allowed
// SGPR operand of v_fma_f32 (no pack/mov cost)
__device__ __forceinline__ float bcastf(float v, int l) {
    return __uint_as_float(__builtin_amdgcn_readlane(__float_as_uint(v), l));
}
// add lane^1 partner via DPP quad_perm [1,0,3,2]
__device__ __forceinline__ float qadd1(float v) {
    int t = __builtin_amdgcn_update_dpp(0, __float_as_int(v), 0xB1, 0xF, 0xF, true);
    return v + __int_as_float(t);
}
// tanh(x) = 1 - 2/(exp2(2*log2e*x)+1); exact saturation, rel err ~1e-6
__device__ __forceinline__ float tanh_fast(float x) {
    float e = __builtin_amdgcn_exp2f(x * 2.885390081777927f);
    return fmaf(-2.0f, __builtin_amdgcn_rcpf(e + 1.0f), 1.0f);
}

extern "C" __global__ void __launch_bounds__(64, 1)
cde_kernel(const float* __restrict__ coeffs,
           const float* __restrict__ W0, const float* __restrict__ b0,
           const float* __restrict__ W1, const float* __restrict__ b1,
           const float* __restrict__ W2, const float* __restrict__ b2,
           const float* __restrict__ W3, const float* __restrict__ b3,
           const float* __restrict__ W4, const float* __restrict__ b4,
           const float* __restrict__ Wf, const float* __restrict__ bf,
           float* __restrict__ out)
{
    const int b = blockIdx.x;
    const int L = threadIdx.x;               // one wave per block
    const float* cb = coeffs + (size_t)b * (TT * DD);

    // stage this block's coeffs in LDS (24 KB) — off the critical path
    __shared__ float xs[TT * DD];
    for (int idx = L; idx < TT * DD; idx += 64) xs[idx] = cb[idx];

    const int quad = L >> 2;                 // neuron owned for layers 1-3
    const int iq   = (quad < HHN) ? quad : (HHN - 1);
    const int par  = L & 1;                  // layer-4 d-slot parity

    // ---- persistent weights in VGPRs (pinned) ----
    // layers 1-3: full column iq per lane (4-way quad redundancy is free)
    float w1l[HN];
    #pragma unroll
    for (int k = 0; k < HN; ++k) { w1l[k] = W1[k * HHN + iq]; pinf(w1l[k]); }
    float w2l[HHN], w3l[HHN];
    #pragma unroll
    for (int k = 0; k < HHN; ++k) {
        w2l[k] = W2[k * HHN + iq]; pinf(w2l[k]);
        w3l[k] = W3[k * HHN + iq]; pinf(w3l[k]);
    }
    float bias1 = b1[iq]; pinf(bias1);
    float bias2 = b2[iq]; pinf(bias2);
    float bias3 = b3[iq]; pinf(bias3);

    // layer 4: lane owns cols c = 3L+q; lanes (2j,2j+1) together cover h-index j
    float w4l[3][HHN], bias4[3];
    #pragma unroll
    for (int q = 0; q < 3; ++q) {
        const int c = 3 * L + q;
        bias4[q] = b4[c]; pinf(bias4[q]);
        #pragma unroll
        for (int k = 0; k < HHN; ++k) { w4l[q][k] = W4[k * (HN * DD) + c]; pinf(w4l[q][k]); }
    }

    __syncthreads();

    // ---- h distributed: lane L holds h[L>>1] (pair-replicated) ----
    const int j = L >> 1;
    float hd = b0[j];
    #pragma unroll
    for (int d = 0; d < DD; ++d) hd = fmaf(xs[d], W0[d * HN + j], hd);

    // per-lane parity-swizzled x windows: even lanes see d=0..2, odd d=3..5
    float xAl[3], xBl[3];
    #pragma unroll
    for (int e = 0; e < 3; ++e) { xAl[e] = xs[par * 3 + e]; xBl[e] = xs[DD + par * 3 + e]; }

    float ys[HN];      // wave-uniform (SGPRs)
    float dxl[3];

    auto bcast32 = [&](float v) {            // distributed (pair) -> 32 SGPRs
        #pragma unroll
        for (int k = 0; k < HN; ++k) ys[k] = bcastf(v, 2 * k);
    };

    // one vector-field eval contracted with dx: ys (SGPR) -> g distributed
    auto evalg = [&]() -> float {
        // layer 1: full 32-dot per lane, 4 accumulators for ILP
        float a0 = 0.f, a1 = 0.f, a2 = 0.f, a3 = 0.f;
        #pragma unroll
        for (int k = 0; k < 8; ++k) {
            a0 = fmaf(ys[k],      w1l[k],      a0);
            a1 = fmaf(ys[k + 8],  w1l[k + 8],  a1);
            a2 = fmaf(ys[k + 16], w1l[k + 16], a2);
            a3 = fmaf(ys[k + 24], w1l[k + 24], a3);
        }
        const float z1 = fmaxf((a0 + a1) + (a2 + a3) + bias1, 0.f);
        float zs[HHN];
        #pragma unroll
        for (int i = 0; i < HHN; ++i) zs[i] = bcastf(z1, 4 * i);

        // layer 2
        float p0 = 0.f, p1 = 0.f;
        #pragma unroll
        for (int k = 0; k < HHN - 1; k += 2) {
            p0 = fmaf(zs[k],     w2l[k],     p0);
            p1 = fmaf(zs[k + 1], w2l[k + 1], p1);
        }
        p0 = fmaf(zs[HHN - 1], w2l[HHN - 1], p0);
        const float z2 = fmaxf(p0 + p1 + bias2, 0.f);
        #pragma unroll
        for (int i = 0; i < HHN; ++i) zs[i] = bcastf(z2, 4 * i);

        // layer 3
        float q0 = 0.f, q1 = 0.f;
        #pragma unroll
        for (int k = 0; k < HHN - 1; k += 2) {
            q0 = fmaf(zs[k],     w3l[k],     q0);
            q1 = fmaf(zs[k + 1], w3l[k + 1], q1);
        }
        q0 = fmaf(zs[HHN - 1], w3l[HHN - 1], q0);
        const float z3 = fmaxf(q0 + q1 + bias3, 0.f);
        #pragma unroll
        for (int i = 0; i < HHN; ++i) zs[i] = bcastf(z3, 4 * i);

        // layer 4 + tanh + dot(dx): 3 cols per lane, independent chains
        float s0[3], s1[3];
        #pragma unroll
        for (int q = 0; q < 3; ++q) {
            s0[q] = bias4[q]; s1[q] = 0.f;
            #pragma unroll
            for (int k = 0; k < HHN - 1; k += 2) {
                s0[q] = fmaf(zs[k],     w4l[q][k],     s0[q]);
                s1[q] = fmaf(zs[k + 1], w4l[q][k + 1], s1[q]);
            }
            s0[q] = fmaf(zs[HHN - 1], w4l[q][HHN - 1], s0[q]);
        }
        float partial = 0.f;
        #pragma unroll
        for (int q = 0; q < 3; ++q)
            partial = fmaf(tanh_fast(s0[q] + s1[q]), dxl[q], partial);
        // g[j] = partial(2j) + partial(2j+1); both lanes of the pair get it
        return qadd1(partial);
    };

    #pragma unroll 1
    for (int t = 0; t < TT - 1; ++t) {
        #pragma unroll
        for (int e = 0; e < 3; ++e) dxl[e] = xBl[e] - xAl[e];

        // prefetch x[t+2] (LDS latency hidden under the step's compute)
        const int tn = (t + 2 < TT) ? (t + 2) : (TT - 1);
        float xNl[3];
        #pragma unroll
        for (int e = 0; e < 3; ++e) xNl[e] = xs[tn * DD + par * 3 + e];

        bcast32(hd);
        const float g1 = evalg();
        float acc = g1;
        float yd  = fmaf(0.5f, g1, hd);
        bcast32(yd);
        const float g2 = evalg();
        acc = fmaf(2.f, g2, acc);
        yd  = fmaf(0.5f, g2, hd);
        bcast32(yd);
        const float g3 = evalg();
        acc = fmaf(2.f, g3, acc);
        yd  = hd + g3;
        bcast32(yd);
        const float g4 = evalg();
        hd = fmaf(1.f / 6.f, acc + g4, hd);

        #pragma unroll
        for (int e = 0; e < 3; ++e) { xAl[e] = xBl[e]; xBl[e] = xNl[e]; }
    }

    // ---- out[b] = h . Wf + bf (each h[j] appears on 2 lanes -> *0.5) ----
    float pz = hd * Wf[j] * 0.5f;
    #pragma unroll
    for (int off = 32; off > 0; off >>= 1) pz += __shfl_xor(pz, off);
    if (L == 0) out[b] = pz + bf[0];
}

extern "C" void kernel_launch(void* const* d_in, const int* in_sizes, int n_in,
                              void* d_out, int out_size, void* d_ws, size_t ws_size,
                              hipStream_t stream) {
    const float* coeffs = (const float*)d_in[0];
    const float* W0 = (const float*)d_in[1];
    const float* b0 = (const float*)d_in[2];
    const float* W1 = (const float*)d_in[3];
    const float* b1 = (const float*)d_in[4];
    const float* W2 = (const float*)d_in[5];
    const float* b2 = (const float*)d_in[6];
    const float* W3 = (const float*)d_in[7];
    const float* b3 = (const float*)d_in[8];
    const float* W4 = (const float*)d_in[9];
    const float* b4 = (const float*)d_in[10];
    const float* Wf = (const float*)d_in[11];
    const float* bf = (const float*)d_in[12];
    float* out = (float*)d_out;

    hipLaunchKernelGGL(cde_kernel, dim3(BB), dim3(64), 0, stream,
                       coeffs, W0, b0, W1, b1, W2, b2, W3, b3, W4, b4, Wf, bf, out);
}

// Round 5
// 1480.381 us; speedup vs baseline: 1.1533x; 1.0030x over previous
//
#include <hip/hip_runtime.h>

#define BB  1024
#define TT  1000
#define DD  6
#define HN  32
#define HHN 15

__device__ __forceinline__ void pinf(float& v) { asm volatile("" : "+v"(v)); }

// wave-uniform broadcast from lane l -> SGPR; feeds v_fma_f32 as its one
// allowed SGPR operand (zero pack cost)
__device__ __forceinline__ float bcastf(float v, int l) {
    return __uint_as_float(__builtin_amdgcn_readlane(__float_as_uint(v), l));
}
// add lane^1 partner via DPP quad_perm [1,0,3,2]
__device__ __forceinline__ float qadd1(float v) {
    int t = __builtin_amdgcn_update_dpp(0, __float_as_int(v), 0xB1, 0xF, 0xF, true);
    return v + __int_as_float(t);
}
// tanh(x) = 1 - 2/(exp2(2*log2e*x)+1); exact saturation, rel err ~1e-6
__device__ __forceinline__ float tanh_fast(float x) {
    float e = __builtin_amdgcn_exp2f(x * 2.885390081777927f);
    return fmaf(-2.0f, __builtin_amdgcn_rcpf(e + 1.0f), 1.0f);
}

extern "C" __global__ void __launch_bounds__(64)
__attribute__((amdgpu_waves_per_eu(1, 1)))
cde_kernel(const float* __restrict__ coeffs,
           const float* __restrict__ W0, const float* __restrict__ b0,
           const float* __restrict__ W1, const float* __restrict__ b1,
           const float* __restrict__ W2, const float* __restrict__ b2,
           const float* __restrict__ W3, const float* __restrict__ b3,
           const float* __restrict__ W4, const float* __restrict__ b4,
           const float* __restrict__ Wf, const float* __restrict__ bf,
           float* __restrict__ out)
{
    const int b = blockIdx.x;
    const int L = threadIdx.x;               // one wave per block
    const float* cb = coeffs + (size_t)b * (TT * DD);

    const int quad = L >> 2;                 // neuron owned for layers 1-3
    const int iq   = (quad < HHN) ? quad : (HHN - 1);
    const int par  = L & 1;                  // layer-4 d-slot parity

    // ---- persistent weights in VGPRs (pinned; ~123 floats, budget 512) ----
    float w1l[HN];
    #pragma unroll
    for (int k = 0; k < HN; ++k) { w1l[k] = W1[k * HHN + iq]; pinf(w1l[k]); }
    float w2l[HHN], w3l[HHN];
    #pragma unroll
    for (int k = 0; k < HHN; ++k) {
        w2l[k] = W2[k * HHN + iq]; pinf(w2l[k]);
        w3l[k] = W3[k * HHN + iq]; pinf(w3l[k]);
    }
    float bias1 = b1[iq]; pinf(bias1);
    float bias2 = b2[iq]; pinf(bias2);
    float bias3 = b3[iq]; pinf(bias3);

    // layer 4: lane owns cols c = 3L+q; lanes (2j,2j+1) together cover h-index j
    float w4l[3][HHN], bias4[3];
    #pragma unroll
    for (int q = 0; q < 3; ++q) {
        const int c = 3 * L + q;
        bias4[q] = b4[c]; pinf(bias4[q]);
        #pragma unroll
        for (int k = 0; k < HHN; ++k) { w4l[q][k] = W4[k * (HN * DD) + c]; pinf(w4l[q][k]); }
    }

    // ---- h distributed: lane L holds h[L>>1] (pair-replicated) ----
    const int j = L >> 1;
    float hd = b0[j];
    #pragma unroll
    for (int d = 0; d < DD; ++d) hd = fmaf(cb[d], W0[d * HN + j], hd);

    // per-lane parity-swizzled x windows: even lanes see d=0..2, odd d=3..5
    float xAl[3], xBl[3];
    #pragma unroll
    for (int e = 0; e < 3; ++e) { xAl[e] = cb[par * 3 + e]; xBl[e] = cb[DD + par * 3 + e]; }

    float ys[HN];      // wave-uniform (SGPRs)
    float dxl[3];

    auto bcast32 = [&](float v) {            // distributed (pair) -> 32 SGPRs
        #pragma unroll
        for (int k = 0; k < HN; ++k) ys[k] = bcastf(v, 2 * k);
    };

    // one vector-field eval contracted with dx: ys (SGPR) -> g distributed
    auto evalg = [&]() -> float {
        // layer 1: full 32-dot per lane, 4 accumulators for ILP (bias folded)
        float a0 = bias1, a1 = 0.f, a2 = 0.f, a3 = 0.f;
        #pragma unroll
        for (int k = 0; k < 8; ++k) {
            a0 = fmaf(ys[k],      w1l[k],      a0);
            a1 = fmaf(ys[k + 8],  w1l[k + 8],  a1);
            a2 = fmaf(ys[k + 16], w1l[k + 16], a2);
            a3 = fmaf(ys[k + 24], w1l[k + 24], a3);
        }
        const float z1 = fmaxf((a0 + a1) + (a2 + a3), 0.f);
        float zs[HHN];
        #pragma unroll
        for (int i = 0; i < HHN; ++i) zs[i] = bcastf(z1, 4 * i);

        // layer 2
        float p0 = bias2, p1 = 0.f;
        #pragma unroll
        for (int k = 0; k < HHN - 1; k += 2) {
            p0 = fmaf(zs[k],     w2l[k],     p0);
            p1 = fmaf(zs[k + 1], w2l[k + 1], p1);
        }
        p0 = fmaf(zs[HHN - 1], w2l[HHN - 1], p0);
        const float z2 = fmaxf(p0 + p1, 0.f);
        #pragma unroll
        for (int i = 0; i < HHN; ++i) zs[i] = bcastf(z2, 4 * i);

        // layer 3
        float q0 = bias3, q1 = 0.f;
        #pragma unroll
        for (int k = 0; k < HHN - 1; k += 2) {
            q0 = fmaf(zs[k],     w3l[k],     q0);
            q1 = fmaf(zs[k + 1], w3l[k + 1], q1);
        }
        q0 = fmaf(zs[HHN - 1], w3l[HHN - 1], q0);
        const float z3 = fmaxf(q0 + q1, 0.f);
        #pragma unroll
        for (int i = 0; i < HHN; ++i) zs[i] = bcastf(z3, 4 * i);

        // layer 4 + tanh + dot(dx): 3 cols per lane, independent chains
        float s0[3], s1[3];
        #pragma unroll
        for (int q = 0; q < 3; ++q) {
            s0[q] = bias4[q]; s1[q] = 0.f;
            #pragma unroll
            for (int k = 0; k < HHN - 1; k += 2) {
                s0[q] = fmaf(zs[k],     w4l[q][k],     s0[q]);
                s1[q] = fmaf(zs[k + 1], w4l[q][k + 1], s1[q]);
            }
            s0[q] = fmaf(zs[HHN - 1], w4l[q][HHN - 1], s0[q]);
        }
        float partial = 0.f;
        #pragma unroll
        for (int q = 0; q < 3; ++q)
            partial = fmaf(tanh_fast(s0[q] + s1[q]), dxl[q], partial);
        // g[j] = partial(2j) + partial(2j+1); both lanes of the pair get it
        return qadd1(partial);
    };

    #pragma unroll 1
    for (int t = 0; t < TT - 1; ++t) {
        #pragma unroll
        for (int e = 0; e < 3; ++e) dxl[e] = xBl[e] - xAl[e];

        // prefetch x[t+2] from global (L2-resident; ~2 steps of slack)
        const int tn = (t + 2 < TT) ? (t + 2) : (TT - 1);
        float xNl[3];
        #pragma unroll
        for (int e = 0; e < 3; ++e) xNl[e] = cb[tn * DD + par * 3 + e];

        bcast32(hd);
        const float g1 = evalg();
        float acc = g1;
        float yd  = fmaf(0.5f, g1, hd);
        bcast32(yd);
        const float g2 = evalg();
        acc = fmaf(2.f, g2, acc);
        yd  = fmaf(0.5f, g2, hd);
        bcast32(yd);
        const float g3 = evalg();
        acc = fmaf(2.f, g3, acc);
        yd  = hd + g3;
        bcast32(yd);
        const float g4 = evalg();
        hd = fmaf(1.f / 6.f, acc + g4, hd);

        #pragma unroll
        for (int e = 0; e < 3; ++e) { xAl[e] = xBl[e]; xBl[e] = xNl[e]; }
    }

    // ---- out[b] = h . Wf + bf (each h[j] appears on 2 lanes -> *0.5) ----
    float pz = hd * Wf[j] * 0.5f;
    #pragma unroll
    for (int off = 32; off > 0; off >>= 1) pz += __shfl_xor(pz, off);
    if (L == 0) out[b] = pz + bf[0];
}

extern "C" void kernel_launch(void* const* d_in, const int* in_sizes, int n_in,
                              void* d_out, int out_size, void* d_ws, size_t ws_size,
                              hipStream_t stream) {
    const float* coeffs = (const float*)d_in[0];
    const float* W0 = (const float*)d_in[1];
    const float* b0 = (const float*)d_in[2];
    const float* W1 = (const float*)d_in[3];
    const float* b1 = (const float*)d_in[4];
    const float* W2 = (const float*)d_in[5];
    const float* b2 = (const float*)d_in[6];
    const float* W3 = (const float*)d_in[7];
    const float* b3 = (const float*)d_in[8];
    const float* W4 = (const float*)d_in[9];
    const float* b4 = (const float*)d_in[10];
    const float* Wf = (const float*)d_in[11];
    const float* bf = (const float*)d_in[12];
    float* out = (float*)d_out;

    hipLaunchKernelGGL(cde_kernel, dim3(BB), dim3(64), 0, stream,
                       coeffs, W0, b0, W1, b1, W2, b2, W3, b3, W4, b4, Wf, bf, out);
}

// Round 8
// 1192.754 us; speedup vs baseline: 1.4315x; 1.2411x over previous
//
#include <hip/hip_runtime.h>

#define BB  1024
#define TT  1000
#define DD  6
#define HN  32
#define HHN 15

typedef _Float16 h2 __attribute__((ext_vector_type(2)));
typedef __fp16  fp16x2 __attribute__((ext_vector_type(2)));

__device__ __forceinline__ void pinf(float& v) { asm volatile("" : "+v"(v)); }
__device__ __forceinline__ void pinh(h2& v) {
    int t = __builtin_bit_cast(int, v);
    asm volatile("" : "+v"(t));
    v = __builtin_bit_cast(h2, t);
}

// RTN pack (setup only): two v_cvt_f16_f32 + pack; unbiased rounding
__device__ __forceinline__ h2 pkh_rtn(float a, float b) {
    h2 r;
    r.x = (_Float16)a;
    r.y = (_Float16)b;
    return r;
}
// fast pack (in-loop): v_cvt_pkrtz_f16_f32, 1 instr
__device__ __forceinline__ h2 pkh(float a, float b) {
    fp16x2 r = __builtin_amdgcn_cvt_pkrtz(a, b);
    return __builtin_bit_cast(h2, r);
}

#if defined(__has_builtin)
#if __has_builtin(__builtin_amdgcn_fdot2)
#define HAVE_FDOT2 1
#endif
#endif
// D = a.x*b.x + a.y*b.y + c, fp32 accumulate (v_dot2_f32_f16: 2 MACs/instr)
__device__ __forceinline__ float dot2(h2 a, h2 b, float c) {
#ifdef HAVE_FDOT2
    return __builtin_amdgcn_fdot2(a, b, c, false);
#else
    return fmaf((float)a.x, (float)b.x, fmaf((float)a.y, (float)b.y, c));
#endif
}

// readlane of a packed pair (uniform result)
__device__ __forceinline__ h2 bch(h2 v, int l) {
    return __builtin_bit_cast(h2, __builtin_amdgcn_readlane(__builtin_bit_cast(int, v), l));
}
// DPP: fetch lane^2 within quad (quad_perm [2,3,0,1])
__device__ __forceinline__ float dpp_xor2(float v) {
    return __int_as_float(__builtin_amdgcn_update_dpp(0, __float_as_int(v), 0x4E, 0xF, 0xF, true));
}
// DPP: fetch lane+4 within 16-lane row (row_shl:4 = 0x104; row_shr was the R6 bug)
__device__ __forceinline__ float dpp_shl4(float v) {
    return __int_as_float(__builtin_amdgcn_update_dpp(0, __float_as_int(v), 0x104, 0xF, 0xF, true));
}
// add lane^1 partner (quad_perm [1,0,3,2])
__device__ __forceinline__ float qadd1(float v) {
    int t = __builtin_amdgcn_update_dpp(0, __float_as_int(v), 0xB1, 0xF, 0xF, true);
    return v + __int_as_float(t);
}
// tanh(x) = 1 - 2/(exp2(2*log2e*x)+1); exact saturation, rel err ~1e-6
__device__ __forceinline__ float tanh_fast(float x) {
    float e = __builtin_amdgcn_exp2f(x * 2.885390081777927f);
    return fmaf(-2.0f, __builtin_amdgcn_rcpf(e + 1.0f), 1.0f);
}

extern "C" __global__ void __launch_bounds__(64)
__attribute__((amdgpu_waves_per_eu(1, 1)))
cde_kernel(const float* __restrict__ coeffs,
           const float* __restrict__ W0, const float* __restrict__ b0,
           const float* __restrict__ W1, const float* __restrict__ b1,
           const float* __restrict__ W2, const float* __restrict__ b2,
           const float* __restrict__ W3, const float* __restrict__ b3,
           const float* __restrict__ W4, const float* __restrict__ b4,
           const float* __restrict__ Wf, const float* __restrict__ bf,
           float* __restrict__ out)
{
    const int b = blockIdx.x;
    const int L = threadIdx.x;               // one wave per block
    const float* cb = coeffs + (size_t)b * (TT * DD);

    const int quad = L >> 2;                 // neuron owned for layers 1-3
    const int iq   = (quad < HHN) ? quad : (HHN - 1);
    const int par  = L & 1;                  // layer-4 d-slot parity

    // ---- persistent weights, f16-packed (RTN) over k-pairs, pinned ----
    h2 w1p[16];
    #pragma unroll
    for (int m = 0; m < 16; ++m) {
        w1p[m] = pkh_rtn(W1[(2 * m) * HHN + iq], W1[(2 * m + 1) * HHN + iq]);
        pinh(w1p[m]);
    }
    h2 w2p[8], w3p[8];
    #pragma unroll
    for (int m = 0; m < 8; ++m) {
        float a2 = W2[(2 * m) * HHN + iq];
        float c2 = (2 * m + 1 < HHN) ? W2[(2 * m + 1) * HHN + iq] : 0.f;
        w2p[m] = pkh_rtn(a2, c2); pinh(w2p[m]);
        float a3 = W3[(2 * m) * HHN + iq];
        float c3 = (2 * m + 1 < HHN) ? W3[(2 * m + 1) * HHN + iq] : 0.f;
        w3p[m] = pkh_rtn(a3, c3); pinh(w3p[m]);
    }
    // quad 15 must produce z == 0 exactly (its slot is the hi half of pair 7)
    float bias1 = (quad < HHN) ? b1[iq] : -1e30f; pinf(bias1);
    float bias2 = (quad < HHN) ? b2[iq] : -1e30f; pinf(bias2);
    float bias3 = (quad < HHN) ? b3[iq] : -1e30f; pinf(bias3);

    // layer 4: lane owns cols c = 3L+q; lanes (2j,2j+1) together cover h-index j
    h2 w4p[3][8]; float bias4[3];
    #pragma unroll
    for (int q = 0; q < 3; ++q) {
        const int c = 3 * L + q;
        bias4[q] = b4[c]; pinf(bias4[q]);
        #pragma unroll
        for (int m = 0; m < 8; ++m) {
            float a4 = W4[(2 * m) * (HN * DD) + c];
            float c4 = (2 * m + 1 < HHN) ? W4[(2 * m + 1) * (HN * DD) + c] : 0.f;
            w4p[q][m] = pkh_rtn(a4, c4); pinh(w4p[q][m]);
        }
    }

    // ---- h distributed fp32: lane L holds h[L>>1] (pair-replicated) ----
    const int j = L >> 1;
    float hd = b0[j];
    #pragma unroll
    for (int d = 0; d < DD; ++d) hd = fmaf(cb[d], W0[d * HN + j], hd);

    // per-lane parity-swizzled x windows: even lanes see d=0..2, odd d=3..5
    float xAl[3], xBl[3];
    #pragma unroll
    for (int e = 0; e < 3; ++e) { xAl[e] = cb[par * 3 + e]; xBl[e] = cb[DD + par * 3 + e]; }

    h2 sy[16];          // wave-uniform packed y
    float dxl[3];

    // distributed y (pair-replicated) -> 16 uniform packed SGPRs
    auto uniy = [&](float yd) {
        const float yp = dpp_xor2(yd);       // lane 4a fetches y[2a+1] from 4a+2
        const h2 ypk = pkh(yd, yp);
        #pragma unroll
        for (int m = 0; m < 16; ++m) sy[m] = bch(ypk, 4 * m);
    };

    // one vector-field eval contracted with dx: sy -> g distributed
    auto evalg = [&]() -> float {
        // layer 1: 16 dot2, 4 chains
        float a0 = bias1, a1 = 0.f, a2 = 0.f, a3 = 0.f;
        #pragma unroll
        for (int m = 0; m < 4; ++m) {
            a0 = dot2(sy[m],      w1p[m],      a0);
            a1 = dot2(sy[m + 4],  w1p[m + 4],  a1);
            a2 = dot2(sy[m + 8],  w1p[m + 8],  a2);
            a3 = dot2(sy[m + 12], w1p[m + 12], a3);
        }
        const float z1 = fmaxf((a0 + a1) + (a2 + a3), 0.f);
        // pack z pairs: lane 8m holds (z[2m], z[2m+1]); z[2m+1] sits on lane 8m+4
        h2 sz[8];
        {
            const float zp = dpp_shl4(z1);
            const h2 zpk = pkh(z1, zp);
            #pragma unroll
            for (int m = 0; m < 8; ++m) sz[m] = bch(zpk, 8 * m);
        }

        // layer 2: 8 dot2, 2 chains
        float p0 = bias2, p1 = 0.f;
        #pragma unroll
        for (int m = 0; m < 4; ++m) {
            p0 = dot2(sz[m],     w2p[m],     p0);
            p1 = dot2(sz[m + 4], w2p[m + 4], p1);
        }
        const float z2 = fmaxf(p0 + p1, 0.f);
        {
            const float zp = dpp_shl4(z2);
            const h2 zpk = pkh(z2, zp);
            #pragma unroll
            for (int m = 0; m < 8; ++m) sz[m] = bch(zpk, 8 * m);
        }

        // layer 3
        float q0 = bias3, q1 = 0.f;
        #pragma unroll
        for (int m = 0; m < 4; ++m) {
            q0 = dot2(sz[m],     w3p[m],     q0);
            q1 = dot2(sz[m + 4], w3p[m + 4], q1);
        }
        const float z3 = fmaxf(q0 + q1, 0.f);
        {
            const float zp = dpp_shl4(z3);
            const h2 zpk = pkh(z3, zp);
            #pragma unroll
            for (int m = 0; m < 8; ++m) sz[m] = bch(zpk, 8 * m);
        }

        // layer 4 + tanh + dot(dx): 3 cols per lane, 8 dot2 each
        float s[3];
        #pragma unroll
        for (int q = 0; q < 3; ++q) {
            s[q] = bias4[q];
            #pragma unroll
            for (int m = 0; m < 8; ++m) s[q] = dot2(sz[m], w4p[q][m], s[q]);
        }
        float partial = 0.f;
        #pragma unroll
        for (int q = 0; q < 3; ++q)
            partial = fmaf(tanh_fast(s[q]), dxl[q], partial);
        // g[j] = partial(2j) + partial(2j+1); both lanes of the pair get it
        return qadd1(partial);
    };

    #pragma unroll 1
    for (int t = 0; t < TT - 1; ++t) {
        #pragma unroll
        for (int e = 0; e < 3; ++e) dxl[e] = xBl[e] - xAl[e];

        // prefetch x[t+2] from global (L2-resident; ~2 steps of slack)
        const int tn = (t + 2 < TT) ? (t + 2) : (TT - 1);
        float xNl[3];
        #pragma unroll
        for (int e = 0; e < 3; ++e) xNl[e] = cb[tn * DD + par * 3 + e];

        uniy(hd);
        const float g1 = evalg();
        float acc = g1;
        float yd  = fmaf(0.5f, g1, hd);
        uniy(yd);
        const float g2 = evalg();
        acc = fmaf(2.f, g2, acc);
        yd  = fmaf(0.5f, g2, hd);
        uniy(yd);
        const float g3 = evalg();
        acc = fmaf(2.f, g3, acc);
        yd  = hd + g3;
        uniy(yd);
        const float g4 = evalg();
        hd = fmaf(1.f / 6.f, acc + g4, hd);

        #pragma unroll
        for (int e = 0; e < 3; ++e) { xAl[e] = xBl[e]; xBl[e] = xNl[e]; }
    }

    // ---- out[b] = h . Wf + bf (each h[j] appears on 2 lanes -> *0.5) ----
    float pz = hd * Wf[j] * 0.5f;
    #pragma unroll
    for (int off = 32; off > 0; off >>= 1) pz += __shfl_xor(pz, off);
    if (L == 0) out[b] = pz + bf[0];
}

extern "C" void kernel_launch(void* const* d_in, const int* in_sizes, int n_in,
                              void* d_out, int out_size, void* d_ws, size_t ws_size,
                              hipStream_t stream) {
    const float* coeffs = (const float*)d_in[0];
    const float* W0 = (const float*)d_in[1];
    const float* b0 = (const float*)d_in[2];
    const float* W1 = (const float*)d_in[3];
    const float* b1 = (const float*)d_in[4];
    const float* W2 = (const float*)d_in[5];
    const float* b2 = (const float*)d_in[6];
    const float* W3 = (const float*)d_in[7];
    const float* b3 = (const float*)d_in[8];
    const float* W4 = (const float*)d_in[9];
    const float* b4 = (const float*)d_in[10];
    const float* Wf = (const float*)d_in[11];
    const float* bf = (const float*)d_in[12];
    float* out = (float*)d_out;

    hipLaunchKernelGGL(cde_kernel, dim3(BB), dim3(64), 0, stream,
                       coeffs, W0, b0, W1, b1, W2, b2, W3, b3, W4, b4, Wf, bf, out);
}